// Round 8
// baseline (232.716 us; speedup 1.0000x reference)
//
#include <hip/hip_runtime.h>
#include <hip/hip_bf16.h>
#include <stdint.h>

typedef __hip_bfloat16 bf16;
typedef __attribute__((ext_vector_type(8))) short bh8;
typedef __attribute__((ext_vector_type(4))) float f32x4;

#define MFMA16(a, b, c) __builtin_amdgcn_mfma_f32_16x16x32_bf16((a), (b), (c), 0, 0, 0)

typedef const __attribute__((address_space(1))) void* gas1_t;
typedef __attribute__((address_space(3))) void* las3_t;

__device__ __forceinline__ void gload_lds16(const void* g, void* l) {
  __builtin_amdgcn_global_load_lds((gas1_t)g, (las3_t)l, 16, 0, 0);
}

__device__ __forceinline__ float bfu2f(unsigned short u) {
  union { unsigned int i; float f; } c;
  c.i = (unsigned int)u << 16;
  return c.f;
}

// ---------------- cast fp32 -> bf16 (vectorized) ----------------
__global__ __launch_bounds__(256) void cast_f32_bf16(const float* __restrict__ x,
                                                     bf16* __restrict__ y, int n4) {
  int i = blockIdx.x * 256 + threadIdx.x;
  if (i >= n4) return;
  float4 v = ((const float4*)x)[i];
  union { ushort4 u; bf16 b[4]; } o;
  o.b[0] = __float2bfloat16(v.x);
  o.b[1] = __float2bfloat16(v.y);
  o.b[2] = __float2bfloat16(v.z);
  o.b[3] = __float2bfloat16(v.w);
  ((ushort4*)y)[i] = o.u;
}

// ---------------- transpose + cast: W (R x C) fp32 -> WT (C x R) bf16 ----------------
__global__ __launch_bounds__(256) void transpose_cast(const float* __restrict__ W,
                                                      bf16* __restrict__ WT, int R, int C) {
  __shared__ float tile[32][33];
  const int tx = threadIdx.x & 31, ty = threadIdx.x >> 5;
  const int bx = blockIdx.x, by = blockIdx.y;
#pragma unroll
  for (int p = 0; p < 4; ++p)
    tile[ty + p * 8][tx] = W[(long)(by * 32 + ty + p * 8) * C + bx * 32 + tx];
  __syncthreads();
#pragma unroll
  for (int p = 0; p < 4; ++p)
    WT[(long)(bx * 32 + ty + p * 8) * R + by * 32 + tx] = __float2bfloat16(tile[tx][ty + p * 8]);
}

// ---------------- GEMM split-K=4: C(MxN) = A(MxK) * BT(NxK)^T, bf16 partials ----------------
// BK=64, XOR-swizzled LDS (T2), 128x128 tile, 4 waves (2x2), grid.z = K-chunk (0..3).
__global__ __launch_bounds__(256) void gemm_bt_sk4(const bf16* __restrict__ A,
                                                   const bf16* __restrict__ BT,
                                                   bf16* __restrict__ c0, bf16* __restrict__ c1,
                                                   bf16* __restrict__ c2, bf16* __restrict__ c3,
                                                   int M, int N, int Kd, int nKs) {
  __shared__ bf16 As[128 * 64];
  __shared__ bf16 Bs[128 * 64];
  const int tid = threadIdx.x, lane = tid & 63, wid = tid >> 6;
  const int wr = wid >> 1, wc = wid & 1;
  const int bx = blockIdx.x, by = blockIdx.y, z = blockIdx.z;

  f32x4 acc[4][4];
#pragma unroll
  for (int m = 0; m < 4; ++m)
#pragma unroll
    for (int n = 0; n < 4; ++n)
#pragma unroll
      for (int r = 0; r < 4; ++r) acc[m][n][r] = 0.0f;

  const long Abase = (long)(by * 128) * Kd;
  const long Bbase = (long)(bx * 128) * Kd;
  const int lr = lane & 15, lh = lane >> 4;
  const int k00 = z * nKs * 64;

  for (int kt = 0; kt < nKs; ++kt) {
    __syncthreads();
    const int k0 = k00 + kt * 64;
#pragma unroll
    for (int i = 0; i < 4; ++i) {
      const int cb = i * 256 + wid * 64;
      const int c = cb + lane;
      const int row = c >> 3, s = c & 7;
      gload_lds16(A + Abase + (long)row * Kd + k0 + (s ^ (row & 7)) * 8, (char*)As + cb * 16);
      gload_lds16(BT + Bbase + (long)row * Kd + k0 + (s ^ (row & 7)) * 8, (char*)Bs + cb * 16);
    }
    __syncthreads();

#pragma unroll
    for (int kk = 0; kk < 2; ++kk) {
      bh8 af[4], bfv[4];
#pragma unroll
      for (int m = 0; m < 4; ++m)
        af[m] = *(const bh8*)((const char*)As +
                              (((wr * 64 + m * 16 + lr) * 128 + kk * 64 + lh * 16) ^
                               ((lr & 7) << 4)));
#pragma unroll
      for (int n = 0; n < 4; ++n)
        bfv[n] = *(const bh8*)((const char*)Bs +
                               (((wc * 64 + n * 16 + lr) * 128 + kk * 64 + lh * 16) ^
                                ((lr & 7) << 4)));
#pragma unroll
      for (int m = 0; m < 4; ++m)
#pragma unroll
        for (int n = 0; n < 4; ++n) acc[m][n] = MFMA16(af[m], bfv[n], acc[m][n]);
    }
  }

  bf16* P = (z == 0) ? c0 : (z == 1) ? c1 : (z == 2) ? c2 : c3;
  const int r0 = by * 128 + wr * 64, c0i = bx * 128 + wc * 64;
  const int lrow = lh * 4;
#pragma unroll
  for (int m = 0; m < 4; ++m)
#pragma unroll
    for (int n = 0; n < 4; ++n)
#pragma unroll
      for (int r = 0; r < 4; ++r)
        P[(long)(r0 + m * 16 + lrow + r) * N + c0i + n * 16 + lr] =
            __float2bfloat16(acc[m][n][r]);
}

// ---------------- out = sum of 4 bf16 partials (fp32 out, vectorized) ----------------
__global__ __launch_bounds__(256) void out_reduce4(float* __restrict__ out,
                                                   const bf16* __restrict__ p0,
                                                   const bf16* __restrict__ p1,
                                                   const bf16* __restrict__ p2,
                                                   const bf16* __restrict__ p3, int n8) {
  int i = blockIdx.x * 256 + threadIdx.x;
  if (i >= n8) return;
  union { bh8 v; ushort s[8]; } a, b, c, d;
  a.v = *(const bh8*)(p0 + (long)i * 8);
  b.v = *(const bh8*)(p1 + (long)i * 8);
  c.v = *(const bh8*)(p2 + (long)i * 8);
  d.v = *(const bh8*)(p3 + (long)i * 8);
  float4 o0, o1;
  float* oo = &o0.x;
#pragma unroll
  for (int e = 0; e < 8; ++e) {
    const float f = bfu2f(a.s[e]) + bfu2f(b.s[e]) + bfu2f(c.s[e]) + bfu2f(d.s[e]);
    if (e < 4) (&o0.x)[e] = f; else (&o1.x)[e - 4] = f;
  }
  (void)oo;
  ((float4*)out)[i * 2] = o0;
  ((float4*)out)[i * 2 + 1] = o1;
}

// ---------------- RoPE (NeoX) + sum 4 bf16 qkv partials + split ----------------
// Trig computed ONCE per (t,d) into LDS (64 sincos/block, was 1280 accurate libm calls).
// Q is PRE-SCALED by 1/sqrt(D).
__global__ __launch_bounds__(256) void rope_split(const bf16* __restrict__ P0,
                                                  const bf16* __restrict__ P1,
                                                  const bf16* __restrict__ P2,
                                                  const bf16* __restrict__ P3,
                                                  const int* __restrict__ pos_ids,
                                                  bf16* __restrict__ Qb, bf16* __restrict__ Kb,
                                                  bf16* __restrict__ VbT) {
  __shared__ float lcs[64], lsn[64];
  const int t = blockIdx.x;
  const int tid = threadIdx.x;
  const float pos = (float)pos_ids[t];
  const float qscale = 0.08838834764831845f;  // 1/sqrt(128)
  const ushort* r0 = (const ushort*)(P0 + (long)t * 3072);
  const ushort* r1 = (const ushort*)(P1 + (long)t * 3072);
  const ushort* r2 = (const ushort*)(P2 + (long)t * 3072);
  const ushort* r3 = (const ushort*)(P3 + (long)t * 3072);

  if (tid < 64) {
    const float inv = exp2f((float)tid * -0.2076205059304594f);  // 10000^(-d/64)
    const float ang = pos * inv;
    float s, c;
    __sincosf(ang, &s, &c);
    lcs[tid] = c;
    lsn[tid] = s;
  }
  __syncthreads();

  // V: sum + cast + transpose to [kh][d][t]
  for (int i = tid; i < 512; i += 256) {
    const int kvh = i >> 7, d = i & 127;
    const float v = bfu2f(r0[2560 + i]) + bfu2f(r1[2560 + i]) + bfu2f(r2[2560 + i]) +
                    bfu2f(r3[2560 + i]);
    VbT[(long)(kvh * 128 + d) * 2048 + t] = __float2bfloat16(v);
  }
  // Q,K: rope over 20 heads x 64 pairs, trig from LDS
  for (int i = tid; i < 1280; i += 256) {
    const int hh = i >> 6, d = i & 63;
    const float c = lcs[d], s = lsn[d];
    const float x1 = bfu2f(r0[hh * 128 + d]) + bfu2f(r1[hh * 128 + d]) +
                     bfu2f(r2[hh * 128 + d]) + bfu2f(r3[hh * 128 + d]);
    const float x2 = bfu2f(r0[hh * 128 + d + 64]) + bfu2f(r1[hh * 128 + d + 64]) +
                     bfu2f(r2[hh * 128 + d + 64]) + bfu2f(r3[hh * 128 + d + 64]);
    const float o1 = x1 * c - x2 * s, o2 = x2 * c + x1 * s;
    if (hh < 16) {
      Qb[(long)t * 2048 + hh * 128 + d] = __float2bfloat16(o1 * qscale);
      Qb[(long)t * 2048 + hh * 128 + d + 64] = __float2bfloat16(o2 * qscale);
    } else {
      Kb[t * 512 + (hh - 16) * 128 + d] = __float2bfloat16(o1);
      Kb[t * 512 + (hh - 16) * 128 + d + 64] = __float2bfloat16(o2);
    }
  }
}

// ---------------- Flash attention partials: swapped-QK in-register softmax ----------------
// S^T = mfma(K_frag, Q_frag): lane holds 16 P values of q-row (lane&15).
// K rows fed in sigma-order so S output regs ARE the PV A-fragment. P never touches LDS.
// launch_bounds(256,2): the 64-VGPR cap from ",4" forced scratch spills (R6).
__global__ __launch_bounds__(256, 2) void attn_partial(const bf16* __restrict__ Qb,
                                                       const bf16* __restrict__ Kb,
                                                       const bf16* __restrict__ VbT,
                                                       bf16* __restrict__ Pctx,
                                                       float* __restrict__ ML) {
  const int h = blockIdx.x;
  const int qb = 31 - blockIdx.y;  // heavy blocks dispatch first
  const int z = blockIdx.z;
  const int kh = h >> 2;
  const int tid = threadIdx.x, lane = tid & 63, w = tid >> 6;
  const int pid = (h * 32 + qb) * 2 + z;

  const int nt = qb + 1;
  const int half = (nt + 1) >> 1;
  const int kt0 = z * half;
  const int kt1 = (z == 0) ? half : nt;

  if (kt0 >= kt1) {  // empty chunk: neutral ML + zeroed partial
    if (tid < 64) {
      ML[pid * 128 + tid] = -1e30f;
      ML[pid * 128 + 64 + tid] = 0.0f;
    }
    ushort4 z4 = make_ushort4(0, 0, 0, 0);
    ushort4* pz = (ushort4*)(Pctx + (long)pid * 8192);
    for (int j = tid; j < 2048; j += 256) pz[j] = z4;
    return;
  }

  __shared__ bf16 Kl[64 * 128];  // swizzle bits: (row&3)|((row&8)>>1)
  __shared__ bf16 Vt[128 * 64];  // swizzle bits: row&7

  const int lr = lane & 15, lh = lane >> 4;
  const int q0w = qb * 64 + w * 16;

  bh8 qf[4];
#pragma unroll
  for (int dc = 0; dc < 4; ++dc)
    qf[dc] = *(const bh8*)&Qb[(long)(q0w + lr) * 2048 + h * 128 + dc * 32 + lh * 8];

  f32x4 ctx[8];
#pragma unroll
  for (int i = 0; i < 8; ++i)
#pragma unroll
    for (int r = 0; r < 4; ++r) ctx[i][r] = 0.0f;
  float mrun = -1e30f, lrun = 0.0f;

  for (int kt = kt0; kt < kt1; ++kt) {
    __syncthreads();
    const long Kbase = ((long)(kt * 64) * 4 + kh) * 128;
#pragma unroll
    for (int i = 0; i < 4; ++i) {
      const int cb = i * 256 + w * 64;
      const int c = cb + lane;
      const int krow = c >> 4, s = c & 15;
      const int g = s ^ ((krow & 3) | ((krow & 8) >> 1));
      gload_lds16(Kb + Kbase + (long)krow * 512 + g * 8, (char*)Kl + cb * 16);
    }
    const long Vbase = (long)kh * 128 * 2048 + kt * 64;
#pragma unroll
    for (int i = 0; i < 4; ++i) {
      const int cb = i * 256 + w * 64;
      const int c = cb + lane;
      const int vrow = c >> 3, s = c & 7;
      gload_lds16(VbT + Vbase + (long)vrow * 2048 + (s ^ (vrow & 7)) * 8, (char*)Vt + cb * 16);
    }
    __syncthreads();

    // S^T = K . Q^T; lane (lr,lh) reg (kc,b,r): S[key=kc*32+lh*8+b*4+r][q=lr]
    f32x4 S[2][2];
#pragma unroll
    for (int kc = 0; kc < 2; ++kc)
#pragma unroll
      for (int b = 0; b < 2; ++b) {
#pragma unroll
        for (int r = 0; r < 4; ++r) S[kc][b][r] = 0.0f;
        const int key = kc * 32 + ((lr >> 2) << 3) + b * 4 + (lr & 3);
        const int kbase = key * 256 + lh * 16;
#pragma unroll
        for (int dc = 0; dc < 4; ++dc) {
          bh8 kf = *(const bh8*)((const char*)Kl + ((kbase + dc * 64) ^ ((lr & 7) << 4)));
          S[kc][b] = MFMA16(kf, qf[dc], S[kc][b]);
        }
      }

    if (kt == qb) {  // causal mask on the diagonal tile only
      const int qg = q0w + lr;
#pragma unroll
      for (int kc = 0; kc < 2; ++kc)
#pragma unroll
        for (int b = 0; b < 2; ++b)
#pragma unroll
          for (int r = 0; r < 4; ++r) {
            const int kg = kt * 64 + kc * 32 + lh * 8 + b * 4 + r;
            if (kg > qg) S[kc][b][r] = -1e30f;
          }
    }

    float pm = -1e30f;
#pragma unroll
    for (int kc = 0; kc < 2; ++kc)
#pragma unroll
      for (int b = 0; b < 2; ++b)
#pragma unroll
        for (int r = 0; r < 4; ++r) pm = fmaxf(pm, S[kc][b][r]);
    pm = fmaxf(pm, __shfl_xor(pm, 16, 64));
    pm = fmaxf(pm, __shfl_xor(pm, 32, 64));

    if (__any(pm > mrun + 4.0f)) {  // defer-max rescale
      const float mnew = fmaxf(mrun, pm);
      const float alpha = __expf(mrun - mnew);
      mrun = mnew;
      lrun *= alpha;
      float a4[4];
#pragma unroll
      for (int r = 0; r < 4; ++r) a4[r] = __shfl(alpha, lh * 4 + r, 64);
#pragma unroll
      for (int i = 0; i < 8; ++i)
#pragma unroll
        for (int r = 0; r < 4; ++r) ctx[i][r] *= a4[r];
    }

    bh8 pa[2];
#pragma unroll
    for (int kc = 0; kc < 2; ++kc) {
      union { bh8 v; bf16 e[8]; } pk;
#pragma unroll
      for (int b = 0; b < 2; ++b)
#pragma unroll
        for (int r = 0; r < 4; ++r) {
          const float p = __expf(S[kc][b][r] - mrun);
          lrun += p;
          pk.e[b * 4 + r] = __float2bfloat16(p);
        }
      pa[kc] = pk.v;
    }

#pragma unroll
    for (int kc = 0; kc < 2; ++kc)
#pragma unroll
      for (int dblk = 0; dblk < 8; ++dblk) {
        const int vrow = dblk * 16 + lr;
        const int voff = (vrow * 128 + kc * 64 + lh * 16) ^ ((lr & 7) << 4);
        bh8 vb = *(const bh8*)((const char*)Vt + voff);
        ctx[dblk] = MFMA16(pa[kc], vb, ctx[dblk]);
      }
  }

  float l = lrun;
  l += __shfl_xor(l, 16, 64);
  l += __shfl_xor(l, 32, 64);
  if (lh == 0) {
    ML[pid * 128 + w * 16 + lr] = mrun;
    ML[pid * 128 + 64 + w * 16 + lr] = l;
  }
#pragma unroll
  for (int dblk = 0; dblk < 8; ++dblk)
#pragma unroll
    for (int r = 0; r < 4; ++r)
      Pctx[(long)pid * 8192 + (w * 16 + lh * 4 + r) * 128 + dblk * 16 + lr] =
          __float2bfloat16(ctx[dblk][r]);
}

// ---------------- merge 2 partials -> normalized ctx (bf16, [t][h*128+d]) ----------------
__global__ __launch_bounds__(256) void attn_merge(const bf16* __restrict__ Pctx,
                                                  const float* __restrict__ ML,
                                                  bf16* __restrict__ out) {
  const int h = blockIdx.x, qb = blockIdx.y;
  const int tid = threadIdx.x;
  const int r = tid >> 2, seg = tid & 3;
  const int pid0 = (h * 32 + qb) * 2;
  const float m0 = ML[pid0 * 128 + r], l0 = ML[pid0 * 128 + 64 + r];
  const float m1 = ML[pid0 * 128 + 128 + r], l1 = ML[pid0 * 128 + 192 + r];
  const float m = fmaxf(m0, m1);
  float a0 = __expf(m0 - m), a1 = __expf(m1 - m);
  const float inv = 1.0f / (l0 * a0 + l1 * a1);
  a0 *= inv;
  a1 *= inv;
  const ushort* p0 = (const ushort*)(Pctx + (long)pid0 * 8192 + r * 128 + seg * 32);
  const ushort* p1 = p0 + 8192;
  bf16* o = out + (long)(qb * 64 + r) * 2048 + h * 128 + seg * 32;
#pragma unroll
  for (int j = 0; j < 4; ++j) {
    union { bh8 v; ushort s[8]; } v0, v1;
    v0.v = *(const bh8*)(p0 + j * 8);
    v1.v = *(const bh8*)(p1 + j * 8);
    union { ushort4 u; bf16 b[4]; } o0, o1;
#pragma unroll
    for (int e = 0; e < 4; ++e) {
      o0.b[e] = __float2bfloat16(bfu2f(v0.s[e]) * a0 + bfu2f(v1.s[e]) * a1);
      o1.b[e] = __float2bfloat16(bfu2f(v0.s[e + 4]) * a0 + bfu2f(v1.s[e + 4]) * a1);
    }
    *(ushort4*)(o + j * 8) = o0.u;
    *(ushort4*)(o + j * 8 + 4) = o1.u;
  }
}

// ---------------- launch ----------------
extern "C" void kernel_launch(void* const* d_in, const int* in_sizes, int n_in,
                              void* d_out, int out_size, void* d_ws, size_t ws_size,
                              hipStream_t stream) {
  const float* hs = (const float*)d_in[0];
  const int* pos = (const int*)d_in[1];
  const float* Wqkv = (const float*)d_in[2];
  const float* Wo = (const float*)d_in[3];
  char* ws = (char*)d_ws;

  // workspace layout (ws_size = 256MB; regions reused across phases):
  // [0,8): hsb -> later ctx
  // [8,20): wqkvT -> later Qb[8,16)+Kb[16,18)+VbT[18,20)
  // [20,28): woT
  // [28,76): qkv bf16 partials x4 (12MB each) -> later Pctx[28,44)+ML[44,44.5)
  // [48,80): gemm2 bf16 partials x4 (8MB each), live after attn_merge
  bf16* hsb = (bf16*)(ws);
  bf16* ctx = (bf16*)(ws);
  bf16* wqkvT = (bf16*)(ws + (8l << 20));
  bf16* Qb = (bf16*)(ws + (8l << 20));
  bf16* Kb = (bf16*)(ws + (16l << 20));
  bf16* VbT = (bf16*)(ws + (18l << 20));
  bf16* woT = (bf16*)(ws + (20l << 20));
  bf16* qkvP0 = (bf16*)(ws + (28l << 20));
  bf16* qkvP1 = (bf16*)(ws + (40l << 20));
  bf16* qkvP2 = (bf16*)(ws + (52l << 20));
  bf16* qkvP3 = (bf16*)(ws + (64l << 20));
  bf16* Pctx = (bf16*)(ws + (28l << 20));
  float* ML = (float*)(ws + (44l << 20));
  bf16* oP0 = (bf16*)(ws + (48l << 20));
  bf16* oP1 = (bf16*)(ws + (56l << 20));
  bf16* oP2 = (bf16*)(ws + (64l << 20));
  bf16* oP3 = (bf16*)(ws + (72l << 20));

  cast_f32_bf16<<<4096, 256, 0, stream>>>(hs, hsb, 2048 * 2048 / 4);
  transpose_cast<<<dim3(3072 / 32, 2048 / 32), 256, 0, stream>>>(Wqkv, wqkvT, 2048, 3072);
  transpose_cast<<<dim3(2048 / 32, 2048 / 32), 256, 0, stream>>>(Wo, woT, 2048, 2048);
  // QKV projection, split-K=4 (8 K-steps of 64 each)
  gemm_bt_sk4<<<dim3(24, 16, 4), 256, 0, stream>>>(hsb, wqkvT, qkvP0, qkvP1, qkvP2, qkvP3,
                                                   2048, 3072, 2048, 8);
  rope_split<<<2048, 256, 0, stream>>>(qkvP0, qkvP1, qkvP2, qkvP3, pos, Qb, Kb, VbT);
  attn_partial<<<dim3(16, 32, 2), 256, 0, stream>>>(Qb, Kb, VbT, Pctx, ML);
  attn_merge<<<dim3(16, 32), 256, 0, stream>>>(Pctx, ML, ctx);
  // Output projection, split-K=4, bf16 partials, then fp32 reduce into d_out
  gemm_bt_sk4<<<dim3(16, 16, 4), 256, 0, stream>>>(ctx, woT, oP0, oP1, oP2, oP3,
                                                   2048, 2048, 2048, 8);
  out_reduce4<<<2048, 256, 0, stream>>>((float*)d_out, oP0, oP1, oP2, oP3, 2048 * 2048 / 8);
}

// Round 9
// 225.676 us; speedup vs baseline: 1.0312x; 1.0312x over previous
//
#include <hip/hip_runtime.h>
#include <hip/hip_bf16.h>
#include <stdint.h>

typedef __hip_bfloat16 bf16;
typedef __attribute__((ext_vector_type(8))) short bh8;
typedef __attribute__((ext_vector_type(4))) float f32x4;

#define MFMA16(a, b, c) __builtin_amdgcn_mfma_f32_16x16x32_bf16((a), (b), (c), 0, 0, 0)

typedef const __attribute__((address_space(1))) void* gas1_t;
typedef __attribute__((address_space(3))) void* las3_t;

__device__ __forceinline__ void gload_lds16(const void* g, void* l) {
  __builtin_amdgcn_global_load_lds((gas1_t)g, (las3_t)l, 16, 0, 0);
}

__device__ __forceinline__ float bfu2f(unsigned short u) {
  union { unsigned int i; float f; } c;
  c.i = (unsigned int)u << 16;
  return c.f;
}

// ---------------- cast fp32 -> bf16 (vectorized) ----------------
__global__ __launch_bounds__(256) void cast_f32_bf16(const float* __restrict__ x,
                                                     bf16* __restrict__ y, int n4) {
  int i = blockIdx.x * 256 + threadIdx.x;
  if (i >= n4) return;
  float4 v = ((const float4*)x)[i];
  union { ushort4 u; bf16 b[4]; } o;
  o.b[0] = __float2bfloat16(v.x);
  o.b[1] = __float2bfloat16(v.y);
  o.b[2] = __float2bfloat16(v.z);
  o.b[3] = __float2bfloat16(v.w);
  ((ushort4*)y)[i] = o.u;
}

// ---------------- transpose + cast: W (R x C) fp32 -> WT (C x R) bf16 ----------------
__global__ __launch_bounds__(256) void transpose_cast(const float* __restrict__ W,
                                                      bf16* __restrict__ WT, int R, int C) {
  __shared__ float tile[32][33];
  const int tx = threadIdx.x & 31, ty = threadIdx.x >> 5;
  const int bx = blockIdx.x, by = blockIdx.y;
#pragma unroll
  for (int p = 0; p < 4; ++p)
    tile[ty + p * 8][tx] = W[(long)(by * 32 + ty + p * 8) * C + bx * 32 + tx];
  __syncthreads();
#pragma unroll
  for (int p = 0; p < 4; ++p)
    WT[(long)(bx * 32 + ty + p * 8) * R + by * 32 + tx] = __float2bfloat16(tile[tx][ty + p * 8]);
}

// ---------------- GEMM split-K=2: C = A * BT^T, BK=64, DOUBLE-BUFFERED LDS ----------------
// Issue-early staging: STAGE(next) -> compute(cur) -> barrier (drains vmcnt AFTER overlap).
// XOR-swizzled LDS (T2), 128x128 tile, 4 waves (2x2), grid.z = K-chunk.
template <bool BF16OUT>
__global__ __launch_bounds__(256) void gemm_bt_sk(const bf16* __restrict__ A,
                                                  const bf16* __restrict__ BT,
                                                  void* __restrict__ C0, void* __restrict__ C1,
                                                  int M, int N, int Kd, int nKs) {
  __shared__ bf16 As[2][128 * 64];
  __shared__ bf16 Bs[2][128 * 64];
  const int tid = threadIdx.x, lane = tid & 63, wid = tid >> 6;
  const int wr = wid >> 1, wc = wid & 1;
  const int bx = blockIdx.x, by = blockIdx.y, z = blockIdx.z;

  f32x4 acc[4][4];
#pragma unroll
  for (int m = 0; m < 4; ++m)
#pragma unroll
    for (int n = 0; n < 4; ++n)
#pragma unroll
      for (int r = 0; r < 4; ++r) acc[m][n][r] = 0.0f;

  const long Abase = (long)(by * 128) * Kd;
  const long Bbase = (long)(bx * 128) * Kd;
  const int lr = lane & 15, lh = lane >> 4;
  const int k00 = z * nKs * 64;

#define G_STAGE(BUF, KT)                                                                   \
  {                                                                                        \
    const int k0 = k00 + (KT) * 64;                                                        \
    _Pragma("unroll") for (int i = 0; i < 4; ++i) {                                        \
      const int cb = i * 256 + wid * 64;                                                   \
      const int c = cb + lane;                                                             \
      const int row = c >> 3, s = c & 7;                                                   \
      gload_lds16(A + Abase + (long)row * Kd + k0 + (s ^ (row & 7)) * 8,                   \
                  (char*)As[BUF] + cb * 16);                                               \
      gload_lds16(BT + Bbase + (long)row * Kd + k0 + (s ^ (row & 7)) * 8,                  \
                  (char*)Bs[BUF] + cb * 16);                                               \
    }                                                                                      \
  }

  G_STAGE(0, 0);
  __syncthreads();  // drains vmcnt(0): buf0 ready
  int cur = 0;
  for (int kt = 0; kt < nKs; ++kt) {
    if (kt + 1 < nKs) G_STAGE(cur ^ 1, kt + 1);  // in flight across compute
    const char* Ab = (const char*)As[cur];
    const char* Bb = (const char*)Bs[cur];
#pragma unroll
    for (int kk = 0; kk < 2; ++kk) {
      bh8 af[4], bfv[4];
#pragma unroll
      for (int m = 0; m < 4; ++m)
        af[m] = *(const bh8*)(Ab + (((wr * 64 + m * 16 + lr) * 128 + kk * 64 + lh * 16) ^
                                    ((lr & 7) << 4)));
#pragma unroll
      for (int n = 0; n < 4; ++n)
        bfv[n] = *(const bh8*)(Bb + (((wc * 64 + n * 16 + lr) * 128 + kk * 64 + lh * 16) ^
                                     ((lr & 7) << 4)));
#pragma unroll
      for (int m = 0; m < 4; ++m)
#pragma unroll
        for (int n = 0; n < 4; ++n) acc[m][n] = MFMA16(af[m], bfv[n], acc[m][n]);
    }
    __syncthreads();  // all reads of cur done; next buffer's loads drained
    cur ^= 1;
  }
#undef G_STAGE

  const int r0 = by * 128 + wr * 64, c0i = bx * 128 + wc * 64;
  const int lrow = lh * 4;
  if (BF16OUT) {
    bf16* P = (bf16*)(z == 0 ? C0 : C1);
#pragma unroll
    for (int m = 0; m < 4; ++m)
#pragma unroll
      for (int n = 0; n < 4; ++n)
#pragma unroll
        for (int r = 0; r < 4; ++r)
          P[(long)(r0 + m * 16 + lrow + r) * N + c0i + n * 16 + lr] =
              __float2bfloat16(acc[m][n][r]);
  } else {
    float* P = (float*)(z == 0 ? C0 : C1);
#pragma unroll
    for (int m = 0; m < 4; ++m)
#pragma unroll
      for (int n = 0; n < 4; ++n)
#pragma unroll
        for (int r = 0; r < 4; ++r)
          P[(long)(r0 + m * 16 + lrow + r) * N + c0i + n * 16 + lr] = acc[m][n][r];
  }
}

// ---------------- out += partial1 (fp32, vectorized) ----------------
__global__ __launch_bounds__(256) void out_reduce(float* __restrict__ out,
                                                  const float* __restrict__ p1, int n4) {
  int i = blockIdx.x * 256 + threadIdx.x;
  if (i >= n4) return;
  float4 a = ((const float4*)out)[i];
  float4 b = ((const float4*)p1)[i];
  a.x += b.x; a.y += b.y; a.z += b.z; a.w += b.w;
  ((float4*)out)[i] = a;
}

// ---------------- RoPE (NeoX) + sum 2 bf16 qkv partials + split ----------------
// Trig once per (t,d) into LDS; Q pre-scaled by 1/sqrt(D).
__global__ __launch_bounds__(256) void rope_split(const bf16* __restrict__ P0,
                                                  const bf16* __restrict__ P1,
                                                  const int* __restrict__ pos_ids,
                                                  bf16* __restrict__ Qb, bf16* __restrict__ Kb,
                                                  bf16* __restrict__ VbT) {
  __shared__ float lcs[64], lsn[64];
  const int t = blockIdx.x;
  const int tid = threadIdx.x;
  const float pos = (float)pos_ids[t];
  const float qscale = 0.08838834764831845f;  // 1/sqrt(128)
  const ushort* r0 = (const ushort*)(P0 + (long)t * 3072);
  const ushort* r1 = (const ushort*)(P1 + (long)t * 3072);

  if (tid < 64) {
    const float inv = exp2f((float)tid * -0.2076205059304594f);  // 10000^(-d/64)
    float s, c;
    __sincosf(pos * inv, &s, &c);
    lcs[tid] = c;
    lsn[tid] = s;
  }
  __syncthreads();

  for (int i = tid; i < 512; i += 256) {
    const int kvh = i >> 7, d = i & 127;
    const float v = bfu2f(r0[2560 + i]) + bfu2f(r1[2560 + i]);
    VbT[(long)(kvh * 128 + d) * 2048 + t] = __float2bfloat16(v);
  }
  for (int i = tid; i < 1280; i += 256) {
    const int hh = i >> 6, d = i & 63;
    const float c = lcs[d], s = lsn[d];
    const float x1 = bfu2f(r0[hh * 128 + d]) + bfu2f(r1[hh * 128 + d]);
    const float x2 = bfu2f(r0[hh * 128 + d + 64]) + bfu2f(r1[hh * 128 + d + 64]);
    const float o1 = x1 * c - x2 * s, o2 = x2 * c + x1 * s;
    if (hh < 16) {
      Qb[(long)t * 2048 + hh * 128 + d] = __float2bfloat16(o1 * qscale);
      Qb[(long)t * 2048 + hh * 128 + d + 64] = __float2bfloat16(o2 * qscale);
    } else {
      Kb[t * 512 + (hh - 16) * 128 + d] = __float2bfloat16(o1);
      Kb[t * 512 + (hh - 16) * 128 + d + 64] = __float2bfloat16(o2);
    }
  }
}

// ---------------- Flash attention partials: swapped-QK in-register softmax + KV dbuf ----------
// S^T = mfma(K_frag, Q_frag): lane holds 16 P values of q-row (lane&15); sigma key-order
// makes S regs the PV A-fragment. Double-buffered K/V staging (issue-early).
// launch_bounds(256,2): ",4" would cap VGPR at 64 -> scratch spills (R6 lesson).
__global__ __launch_bounds__(256, 2) void attn_partial(const bf16* __restrict__ Qb,
                                                       const bf16* __restrict__ Kb,
                                                       const bf16* __restrict__ VbT,
                                                       bf16* __restrict__ Pctx,
                                                       float* __restrict__ ML) {
  const int h = blockIdx.x;
  const int qb = 31 - blockIdx.y;  // heavy blocks dispatch first
  const int z = blockIdx.z;
  const int kh = h >> 2;
  const int tid = threadIdx.x, lane = tid & 63, w = tid >> 6;
  const int pid = (h * 32 + qb) * 2 + z;

  const int nt = qb + 1;
  const int half = (nt + 1) >> 1;
  const int kt0 = z * half;
  const int kt1 = (z == 0) ? half : nt;

  if (kt0 >= kt1) {  // empty chunk: neutral ML + zeroed partial
    if (tid < 64) {
      ML[pid * 128 + tid] = -1e30f;
      ML[pid * 128 + 64 + tid] = 0.0f;
    }
    ushort4 z4 = make_ushort4(0, 0, 0, 0);
    ushort4* pz = (ushort4*)(Pctx + (long)pid * 8192);
    for (int j = tid; j < 2048; j += 256) pz[j] = z4;
    return;
  }

  __shared__ bf16 Kl[2][64 * 128];  // swizzle bits: (row&3)|((row&8)>>1)
  __shared__ bf16 Vt[2][128 * 64];  // swizzle bits: row&7

  const int lr = lane & 15, lh = lane >> 4;
  const int q0w = qb * 64 + w * 16;

#define KV_STAGE(BUF, KT)                                                                  \
  {                                                                                        \
    const long Kbase = ((long)((KT) * 64) * 4 + kh) * 128;                                 \
    _Pragma("unroll") for (int i = 0; i < 4; ++i) {                                        \
      const int cb = i * 256 + w * 64;                                                     \
      const int c = cb + lane;                                                             \
      const int krow = c >> 4, s = c & 15;                                                 \
      const int g = s ^ ((krow & 3) | ((krow & 8) >> 1));                                  \
      gload_lds16(Kb + Kbase + (long)krow * 512 + g * 8, (char*)Kl[BUF] + cb * 16);        \
    }                                                                                      \
    const long Vbase = (long)kh * 128 * 2048 + (KT) * 64;                                  \
    _Pragma("unroll") for (int i = 0; i < 4; ++i) {                                        \
      const int cb = i * 256 + w * 64;                                                     \
      const int c = cb + lane;                                                             \
      const int vrow = c >> 3, s = c & 7;                                                  \
      gload_lds16(VbT + Vbase + (long)vrow * 2048 + (s ^ (vrow & 7)) * 8,                  \
                  (char*)Vt[BUF] + cb * 16);                                               \
    }                                                                                      \
  }

  bh8 qf[4];
#pragma unroll
  for (int dc = 0; dc < 4; ++dc)
    qf[dc] = *(const bh8*)&Qb[(long)(q0w + lr) * 2048 + h * 128 + dc * 32 + lh * 8];

  f32x4 ctx[8];
#pragma unroll
  for (int i = 0; i < 8; ++i)
#pragma unroll
    for (int r = 0; r < 4; ++r) ctx[i][r] = 0.0f;
  float mrun = -1e30f, lrun = 0.0f;

  KV_STAGE(0, kt0);
  __syncthreads();
  int cur = 0;
  for (int kt = kt0; kt < kt1; ++kt) {
    if (kt + 1 < kt1) KV_STAGE(cur ^ 1, kt + 1);  // in flight across compute
    const char* Kc = (const char*)Kl[cur];
    const char* Vc = (const char*)Vt[cur];

    // S^T = K . Q^T; lane (lr,lh) reg (kc,b,r): S[key=kc*32+lh*8+b*4+r][q=lr]
    f32x4 S[2][2];
#pragma unroll
    for (int kc = 0; kc < 2; ++kc)
#pragma unroll
      for (int b = 0; b < 2; ++b) {
#pragma unroll
        for (int r = 0; r < 4; ++r) S[kc][b][r] = 0.0f;
        const int key = kc * 32 + ((lr >> 2) << 3) + b * 4 + (lr & 3);
        const int kbase = key * 256 + lh * 16;
#pragma unroll
        for (int dc = 0; dc < 4; ++dc) {
          bh8 kf = *(const bh8*)(Kc + ((kbase + dc * 64) ^ ((lr & 7) << 4)));
          S[kc][b] = MFMA16(kf, qf[dc], S[kc][b]);
        }
      }

    if (kt == qb) {  // causal mask on the diagonal tile only
      const int qg = q0w + lr;
#pragma unroll
      for (int kc = 0; kc < 2; ++kc)
#pragma unroll
        for (int b = 0; b < 2; ++b)
#pragma unroll
          for (int r = 0; r < 4; ++r) {
            const int kg = kt * 64 + kc * 32 + lh * 8 + b * 4 + r;
            if (kg > qg) S[kc][b][r] = -1e30f;
          }
    }

    float pm = -1e30f;
#pragma unroll
    for (int kc = 0; kc < 2; ++kc)
#pragma unroll
      for (int b = 0; b < 2; ++b)
#pragma unroll
        for (int r = 0; r < 4; ++r) pm = fmaxf(pm, S[kc][b][r]);
    pm = fmaxf(pm, __shfl_xor(pm, 16, 64));
    pm = fmaxf(pm, __shfl_xor(pm, 32, 64));

    if (__any(pm > mrun + 4.0f)) {  // defer-max rescale
      const float mnew = fmaxf(mrun, pm);
      const float alpha = __expf(mrun - mnew);
      mrun = mnew;
      lrun *= alpha;
      float a4[4];
#pragma unroll
      for (int r = 0; r < 4; ++r) a4[r] = __shfl(alpha, lh * 4 + r, 64);
#pragma unroll
      for (int i = 0; i < 8; ++i)
#pragma unroll
        for (int r = 0; r < 4; ++r) ctx[i][r] *= a4[r];
    }

    bh8 pa[2];
#pragma unroll
    for (int kc = 0; kc < 2; ++kc) {
      union { bh8 v; bf16 e[8]; } pk;
#pragma unroll
      for (int b = 0; b < 2; ++b)
#pragma unroll
        for (int r = 0; r < 4; ++r) {
          const float p = __expf(S[kc][b][r] - mrun);
          lrun += p;
          pk.e[b * 4 + r] = __float2bfloat16(p);
        }
      pa[kc] = pk.v;
    }

#pragma unroll
    for (int kc = 0; kc < 2; ++kc)
#pragma unroll
      for (int dblk = 0; dblk < 8; ++dblk) {
        const int vrow = dblk * 16 + lr;
        const int voff = (vrow * 128 + kc * 64 + lh * 16) ^ ((lr & 7) << 4);
        bh8 vb = *(const bh8*)(Vc + voff);
        ctx[dblk] = MFMA16(pa[kc], vb, ctx[dblk]);
      }

    __syncthreads();  // reads of cur done by all waves; next buffer's loads drained
    cur ^= 1;
  }
#undef KV_STAGE

  float l = lrun;
  l += __shfl_xor(l, 16, 64);
  l += __shfl_xor(l, 32, 64);
  if (lh == 0) {
    ML[pid * 128 + w * 16 + lr] = mrun;
    ML[pid * 128 + 64 + w * 16 + lr] = l;
  }
#pragma unroll
  for (int dblk = 0; dblk < 8; ++dblk)
#pragma unroll
    for (int r = 0; r < 4; ++r)
      Pctx[(long)pid * 8192 + (w * 16 + lh * 4 + r) * 128 + dblk * 16 + lr] =
          __float2bfloat16(ctx[dblk][r]);
}

// ---------------- merge 2 partials -> normalized ctx (bf16, [t][h*128+d]) ----------------
__global__ __launch_bounds__(256) void attn_merge(const bf16* __restrict__ Pctx,
                                                  const float* __restrict__ ML,
                                                  bf16* __restrict__ out) {
  const int h = blockIdx.x, qb = blockIdx.y;
  const int tid = threadIdx.x;
  const int r = tid >> 2, seg = tid & 3;
  const int pid0 = (h * 32 + qb) * 2;
  const float m0 = ML[pid0 * 128 + r], l0 = ML[pid0 * 128 + 64 + r];
  const float m1 = ML[pid0 * 128 + 128 + r], l1 = ML[pid0 * 128 + 192 + r];
  const float m = fmaxf(m0, m1);
  float a0 = __expf(m0 - m), a1 = __expf(m1 - m);
  const float inv = 1.0f / (l0 * a0 + l1 * a1);
  a0 *= inv;
  a1 *= inv;
  const ushort* p0 = (const ushort*)(Pctx + (long)pid0 * 8192 + r * 128 + seg * 32);
  const ushort* p1 = p0 + 8192;
  bf16* o = out + (long)(qb * 64 + r) * 2048 + h * 128 + seg * 32;
#pragma unroll
  for (int j = 0; j < 4; ++j) {
    union { bh8 v; ushort s[8]; } v0, v1;
    v0.v = *(const bh8*)(p0 + j * 8);
    v1.v = *(const bh8*)(p1 + j * 8);
    union { ushort4 u; bf16 b[4]; } o0, o1;
#pragma unroll
    for (int e = 0; e < 4; ++e) {
      o0.b[e] = __float2bfloat16(bfu2f(v0.s[e]) * a0 + bfu2f(v1.s[e]) * a1);
      o1.b[e] = __float2bfloat16(bfu2f(v0.s[e + 4]) * a0 + bfu2f(v1.s[e + 4]) * a1);
    }
    *(ushort4*)(o + j * 8) = o0.u;
    *(ushort4*)(o + j * 8 + 4) = o1.u;
  }
}

// ---------------- launch ----------------
extern "C" void kernel_launch(void* const* d_in, const int* in_sizes, int n_in,
                              void* d_out, int out_size, void* d_ws, size_t ws_size,
                              hipStream_t stream) {
  const float* hs = (const float*)d_in[0];
  const int* pos = (const int*)d_in[1];
  const float* Wqkv = (const float*)d_in[2];
  const float* Wo = (const float*)d_in[3];
  char* ws = (char*)d_ws;

  // workspace layout:
  // [0,8): hsb -> later ctx
  // [8,20): wqkvT -> later Qb[8,16)+Kb[16,18)+VbT[18,20)
  // [20,28): woT
  // [28,40)+[40,52): qkv bf16 partials -> later Pctx[28,44)+ML[44,44.5) -> later outP1[28,44)
  bf16* hsb = (bf16*)(ws);
  bf16* ctx = (bf16*)(ws);
  bf16* wqkvT = (bf16*)(ws + (8l << 20));
  bf16* Qb = (bf16*)(ws + (8l << 20));
  bf16* Kb = (bf16*)(ws + (16l << 20));
  bf16* VbT = (bf16*)(ws + (18l << 20));
  bf16* woT = (bf16*)(ws + (20l << 20));
  bf16* qkvP0 = (bf16*)(ws + (28l << 20));
  bf16* qkvP1 = (bf16*)(ws + (40l << 20));
  bf16* Pctx = (bf16*)(ws + (28l << 20));
  float* ML = (float*)(ws + (44l << 20));
  float* outP1 = (float*)(ws + (28l << 20));

  cast_f32_bf16<<<4096, 256, 0, stream>>>(hs, hsb, 2048 * 2048 / 4);
  transpose_cast<<<dim3(3072 / 32, 2048 / 32), 256, 0, stream>>>(Wqkv, wqkvT, 2048, 3072);
  transpose_cast<<<dim3(2048 / 32, 2048 / 32), 256, 0, stream>>>(Wo, woT, 2048, 2048);
  gemm_bt_sk<true><<<dim3(24, 16, 2), 256, 0, stream>>>(hsb, wqkvT, qkvP0, qkvP1,
                                                        2048, 3072, 2048, 16);
  rope_split<<<2048, 256, 0, stream>>>(qkvP0, qkvP1, pos, Qb, Kb, VbT);
  attn_partial<<<dim3(16, 32, 2), 256, 0, stream>>>(Qb, Kb, VbT, Pctx, ML);
  attn_merge<<<dim3(16, 32), 256, 0, stream>>>(Pctx, ML, ctx);
  gemm_bt_sk<false><<<dim3(16, 16, 2), 256, 0, stream>>>(ctx, woT, d_out, outP1,
                                                         2048, 2048, 2048, 16);
  out_reduce<<<4096, 256, 0, stream>>>((float*)d_out, outP1, 2048 * 2048 / 4);
}

// Round 12
// 222.483 us; speedup vs baseline: 1.0460x; 1.0144x over previous
//
#include <hip/hip_runtime.h>
#include <hip/hip_bf16.h>
#include <stdint.h>

typedef __hip_bfloat16 bf16;
typedef __attribute__((ext_vector_type(8))) short bh8;
typedef __attribute__((ext_vector_type(4))) float f32x4;

#define MFMA16(a, b, c) __builtin_amdgcn_mfma_f32_16x16x32_bf16((a), (b), (c), 0, 0, 0)
#define VMCNT(N) asm volatile("s_waitcnt vmcnt(" #N ")" ::: "memory")

typedef const __attribute__((address_space(1))) void* gas1_t;
typedef __attribute__((address_space(3))) void* las3_t;

__device__ __forceinline__ void gload_lds16(const void* g, void* l) {
  __builtin_amdgcn_global_load_lds((gas1_t)g, (las3_t)l, 16, 0, 0);
}

__device__ __forceinline__ float bfu2f(unsigned short u) {
  union { unsigned int i; float f; } c;
  c.i = (unsigned int)u << 16;
  return c.f;
}

// ---------------- fused prep: cast hs -> bf16 ; transpose Wqkv, Wo -> bf16 ----------------
__global__ __launch_bounds__(256) void prep(const float* __restrict__ hs, bf16* __restrict__ hsb,
                                            const float* __restrict__ Wqkv,
                                            bf16* __restrict__ wqkvT,
                                            const float* __restrict__ Wo,
                                            bf16* __restrict__ woT) {
  const int b = blockIdx.x, tid = threadIdx.x;
  if (b < 4096) {  // cast 2048x2048 fp32 -> bf16
    const int i = b * 256 + tid;
    float4 v = ((const float4*)hs)[i];
    union { ushort4 u; bf16 bb[4]; } o;
    o.bb[0] = __float2bfloat16(v.x);
    o.bb[1] = __float2bfloat16(v.y);
    o.bb[2] = __float2bfloat16(v.z);
    o.bb[3] = __float2bfloat16(v.w);
    ((ushort4*)hsb)[i] = o.u;
    return;
  }
  __shared__ float tile[32][33];
  const float* W;
  bf16* WT;
  int bx, by, R, C;
  if (b < 4096 + 6144) {  // Wqkv (2048 x 3072) -> (3072 x 2048)
    const int bb = b - 4096;
    bx = bb % 96; by = bb / 96; R = 2048; C = 3072; W = Wqkv; WT = wqkvT;
  } else {  // Wo (2048 x 2048) -> (2048 x 2048)
    const int bb = b - 10240;
    bx = bb % 64; by = bb / 64; R = 2048; C = 2048; W = Wo; WT = woT;
  }
  const int tx = tid & 31, ty = tid >> 5;
#pragma unroll
  for (int p = 0; p < 4; ++p)
    tile[ty + p * 8][tx] = W[(long)(by * 32 + ty + p * 8) * C + bx * 32 + tx];
  __syncthreads();
#pragma unroll
  for (int p = 0; p < 4; ++p)
    WT[(long)(bx * 32 + ty + p * 8) * R + by * 32 + tx] = __float2bfloat16(tile[tx][ty + p * 8]);
}

// ---------------- GEMM split-K=2: BK=64, dbuf + COUNTED vmcnt (T4) + XCD swizzle (T1) -------
// STAGE(next) -> vmcnt(8) [prev stage done, next stays IN FLIGHT across barriers]
// -> s_barrier -> compute(cur) -> s_barrier.  8 gload_lds per wave per stage.
template <bool BF16OUT>
__global__ __launch_bounds__(256) void gemm_bt_sk(const bf16* __restrict__ A,
                                                  const bf16* __restrict__ BT,
                                                  void* __restrict__ C0, void* __restrict__ C1,
                                                  int M, int N, int Kd, int nKs) {
  __shared__ bf16 As[2][128 * 64];
  __shared__ bf16 Bs[2][128 * 64];
  const int tid = threadIdx.x, lane = tid & 63, wid = tid >> 6;
  const int wr = wid >> 1, wc = wid & 1;

  // XCD-aware bijective swizzle (nwg % 8 == 0): consecutive work-ids share an XCD L2.
  const int gx = gridDim.x, gy = gridDim.y;
  const int nwg = gx * gy * gridDim.z;
  const int orig = (blockIdx.z * gy + blockIdx.y) * gx + blockIdx.x;
  const int widq = (orig & 7) * (nwg >> 3) + (orig >> 3);
  const int bx = widq % gx, by = (widq / gx) % gy, z = widq / (gx * gy);

  f32x4 acc[4][4];
#pragma unroll
  for (int m = 0; m < 4; ++m)
#pragma unroll
    for (int n = 0; n < 4; ++n)
#pragma unroll
      for (int r = 0; r < 4; ++r) acc[m][n][r] = 0.0f;

  const long Abase = (long)(by * 128) * Kd;
  const long Bbase = (long)(bx * 128) * Kd;
  const int lr = lane & 15, lh = lane >> 4;
  const int k00 = z * nKs * 64;

#define G_STAGE(BUF, KT)                                                                   \
  {                                                                                        \
    const int k0 = k00 + (KT) * 64;                                                        \
    _Pragma("unroll") for (int i = 0; i < 4; ++i) {                                        \
      const int cb = i * 256 + wid * 64;                                                   \
      const int c = cb + lane;                                                             \
      const int row = c >> 3, s = c & 7;                                                   \
      gload_lds16(A + Abase + (long)row * Kd + k0 + (s ^ (row & 7)) * 8,                   \
                  (char*)As[BUF] + cb * 16);                                               \
      gload_lds16(BT + Bbase + (long)row * Kd + k0 + (s ^ (row & 7)) * 8,                  \
                  (char*)Bs[BUF] + cb * 16);                                               \
    }                                                                                      \
  }

  G_STAGE(0, 0);
  int cur = 0;
  for (int kt = 0; kt < nKs; ++kt) {
    if (kt + 1 < nKs) {
      G_STAGE(cur ^ 1, kt + 1);  // 16 outstanding; wait oldest 8 (prev stage)
      VMCNT(8);
    } else {
      VMCNT(0);
    }
    __builtin_amdgcn_sched_barrier(0);
    __builtin_amdgcn_s_barrier();  // all waves' stage-kt loads complete
    const char* Ab = (const char*)As[cur];
    const char* Bb = (const char*)Bs[cur];
#pragma unroll
    for (int kk = 0; kk < 2; ++kk) {
      bh8 af[4], bfv[4];
#pragma unroll
      for (int m = 0; m < 4; ++m)
        af[m] = *(const bh8*)(Ab + (((wr * 64 + m * 16 + lr) * 128 + kk * 64 + lh * 16) ^
                                    ((lr & 7) << 4)));
#pragma unroll
      for (int n = 0; n < 4; ++n)
        bfv[n] = *(const bh8*)(Bb + (((wc * 64 + n * 16 + lr) * 128 + kk * 64 + lh * 16) ^
                                     ((lr & 7) << 4)));
#pragma unroll
      for (int m = 0; m < 4; ++m)
#pragma unroll
        for (int n = 0; n < 4; ++n) acc[m][n] = MFMA16(af[m], bfv[n], acc[m][n]);
    }
    __builtin_amdgcn_s_barrier();  // reads of cur done; safe to re-stage next iter
    cur ^= 1;
  }
#undef G_STAGE

  const int r0 = by * 128 + wr * 64, c0i = bx * 128 + wc * 64;
  const int lrow = lh * 4;
  if (BF16OUT) {
    bf16* P = (bf16*)(z == 0 ? C0 : C1);
#pragma unroll
    for (int m = 0; m < 4; ++m)
#pragma unroll
      for (int n = 0; n < 4; ++n)
#pragma unroll
        for (int r = 0; r < 4; ++r)
          P[(long)(r0 + m * 16 + lrow + r) * N + c0i + n * 16 + lr] =
              __float2bfloat16(acc[m][n][r]);
  } else {
    float* P = (float*)(z == 0 ? C0 : C1);
#pragma unroll
    for (int m = 0; m < 4; ++m)
#pragma unroll
      for (int n = 0; n < 4; ++n)
#pragma unroll
        for (int r = 0; r < 4; ++r)
          P[(long)(r0 + m * 16 + lrow + r) * N + c0i + n * 16 + lr] = acc[m][n][r];
  }
}

// ---------------- out += partial1 (fp32, vectorized) ----------------
__global__ __launch_bounds__(256) void out_reduce(float* __restrict__ out,
                                                  const float* __restrict__ p1, int n4) {
  int i = blockIdx.x * 256 + threadIdx.x;
  if (i >= n4) return;
  float4 a = ((const float4*)out)[i];
  float4 b = ((const float4*)p1)[i];
  a.x += b.x; a.y += b.y; a.z += b.z; a.w += b.w;
  ((float4*)out)[i] = a;
}

// ---------------- RoPE (NeoX) + sum 2 bf16 qkv partials + split ----------------
__global__ __launch_bounds__(256) void rope_split(const bf16* __restrict__ P0,
                                                  const bf16* __restrict__ P1,
                                                  const int* __restrict__ pos_ids,
                                                  bf16* __restrict__ Qb, bf16* __restrict__ Kb,
                                                  bf16* __restrict__ VbT) {
  __shared__ float lcs[64], lsn[64];
  const int t = blockIdx.x;
  const int tid = threadIdx.x;
  const float pos = (float)pos_ids[t];
  const float qscale = 0.08838834764831845f;  // 1/sqrt(128)
  const ushort* r0 = (const ushort*)(P0 + (long)t * 3072);
  const ushort* r1 = (const ushort*)(P1 + (long)t * 3072);

  if (tid < 64) {
    const float inv = exp2f((float)tid * -0.2076205059304594f);  // 10000^(-d/64)
    float s, c;
    __sincosf(pos * inv, &s, &c);
    lcs[tid] = c;
    lsn[tid] = s;
  }
  __syncthreads();

  for (int i = tid; i < 512; i += 256) {
    const int kvh = i >> 7, d = i & 127;
    const float v = bfu2f(r0[2560 + i]) + bfu2f(r1[2560 + i]);
    VbT[(long)(kvh * 128 + d) * 2048 + t] = __float2bfloat16(v);
  }
  for (int i = tid; i < 1280; i += 256) {
    const int hh = i >> 6, d = i & 63;
    const float c = lcs[d], s = lsn[d];
    const float x1 = bfu2f(r0[hh * 128 + d]) + bfu2f(r1[hh * 128 + d]);
    const float x2 = bfu2f(r0[hh * 128 + d + 64]) + bfu2f(r1[hh * 128 + d + 64]);
    const float o1 = x1 * c - x2 * s, o2 = x2 * c + x1 * s;
    if (hh < 16) {
      Qb[(long)t * 2048 + hh * 128 + d] = __float2bfloat16(o1 * qscale);
      Qb[(long)t * 2048 + hh * 128 + d + 64] = __float2bfloat16(o2 * qscale);
    } else {
      Kb[t * 512 + (hh - 16) * 128 + d] = __float2bfloat16(o1);
      Kb[t * 512 + (hh - 16) * 128 + d + 64] = __float2bfloat16(o2);
    }
  }
}

// ---------------- Flash attention partials: swapped-QK in-reg softmax + counted-vmcnt dbuf ----
// launch_bounds(256,2): ",4" would cap VGPR at 64 -> scratch spills (R6 lesson).
__global__ __launch_bounds__(256, 2) void attn_partial(const bf16* __restrict__ Qb,
                                                       const bf16* __restrict__ Kb,
                                                       const bf16* __restrict__ VbT,
                                                       bf16* __restrict__ Pctx,
                                                       float* __restrict__ ML) {
  const int h = blockIdx.x;
  const int qb = 31 - blockIdx.y;  // heavy blocks dispatch first
  const int z = blockIdx.z;
  const int kh = h >> 2;
  const int tid = threadIdx.x, lane = tid & 63, w = tid >> 6;
  const int pid = (h * 32 + qb) * 2 + z;

  const int nt = qb + 1;
  const int half = (nt + 1) >> 1;
  const int kt0 = z * half;
  const int kt1 = (z == 0) ? half : nt;

  if (kt0 >= kt1) {  // empty chunk: neutral ML + zeroed partial
    if (tid < 64) {
      ML[pid * 128 + tid] = -1e30f;
      ML[pid * 128 + 64 + tid] = 0.0f;
    }
    ushort4 z4 = make_ushort4(0, 0, 0, 0);
    ushort4* pz = (ushort4*)(Pctx + (long)pid * 8192);
    for (int j = tid; j < 2048; j += 256) pz[j] = z4;
    return;
  }

  __shared__ bf16 Kl[2][64 * 128];  // swizzle bits: (row&3)|((row&8)>>1)
  __shared__ bf16 Vt[2][128 * 64];  // swizzle bits: row&7

  const int lr = lane & 15, lh = lane >> 4;
  const int q0w = qb * 64 + w * 16;

#define KV_STAGE(BUF, KT)                                                                  \
  {                                                                                        \
    const long Kbase = ((long)((KT) * 64) * 4 + kh) * 128;                                 \
    _Pragma("unroll") for (int i = 0; i < 4; ++i) {                                        \
      const int cb = i * 256 + w * 64;                                                     \
      const int c = cb + lane;                                                             \
      const int krow = c >> 4, s = c & 15;                                                 \
      const int g = s ^ ((krow & 3) | ((krow & 8) >> 1));                                  \
      gload_lds16(Kb + Kbase + (long)krow * 512 + g * 8, (char*)Kl[BUF] + cb * 16);        \
    }                                                                                      \
    const long Vbase = (long)kh * 128 * 2048 + (KT) * 64;                                  \
    _Pragma("unroll") for (int i = 0; i < 4; ++i) {                                        \
      const int cb = i * 256 + w * 64;                                                     \
      const int c = cb + lane;                                                             \
      const int vrow = c >> 3, s = c & 7;                                                  \
      gload_lds16(VbT + Vbase + (long)vrow * 2048 + (s ^ (vrow & 7)) * 8,                  \
                  (char*)Vt[BUF] + cb * 16);                                               \
    }                                                                                      \
  }

  bh8 qf[4];
#pragma unroll
  for (int dc = 0; dc < 4; ++dc)
    qf[dc] = *(const bh8*)&Qb[(long)(q0w + lr) * 2048 + h * 128 + dc * 32 + lh * 8];

  f32x4 ctx[8];
#pragma unroll
  for (int i = 0; i < 8; ++i)
#pragma unroll
    for (int r = 0; r < 4; ++r) ctx[i][r] = 0.0f;
  float mrun = -1e30f, lrun = 0.0f;

  KV_STAGE(0, kt0);
  int cur = 0;
  for (int kt = kt0; kt < kt1; ++kt) {
    if (kt + 1 < kt1) {
      KV_STAGE(cur ^ 1, kt + 1);  // stays in flight across barriers
      VMCNT(8);
    } else {
      VMCNT(0);
    }
    __builtin_amdgcn_sched_barrier(0);
    __builtin_amdgcn_s_barrier();  // all waves' stage-kt loads complete
    const char* Kc = (const char*)Kl[cur];
    const char* Vc = (const char*)Vt[cur];

    // S^T = K . Q^T; lane (lr,lh) reg (kc,b,r): S[key=kc*32+lh*8+b*4+r][q=lr]
    f32x4 S[2][2];
#pragma unroll
    for (int kc = 0; kc < 2; ++kc)
#pragma unroll
      for (int b = 0; b < 2; ++b) {
#pragma unroll
        for (int r = 0; r < 4; ++r) S[kc][b][r] = 0.0f;
        const int key = kc * 32 + ((lr >> 2) << 3) + b * 4 + (lr & 3);
        const int kbase = key * 256 + lh * 16;
#pragma unroll
        for (int dc = 0; dc < 4; ++dc) {
          bh8 kf = *(const bh8*)(Kc + ((kbase + dc * 64) ^ ((lr & 7) << 4)));
          S[kc][b] = MFMA16(kf, qf[dc], S[kc][b]);
        }
      }

    if (kt == qb) {  // causal mask on the diagonal tile only
      const int qg = q0w + lr;
#pragma unroll
      for (int kc = 0; kc < 2; ++kc)
#pragma unroll
        for (int b = 0; b < 2; ++b)
#pragma unroll
          for (int r = 0; r < 4; ++r) {
            const int kg = kt * 64 + kc * 32 + lh * 8 + b * 4 + r;
            if (kg > qg) S[kc][b][r] = -1e30f;
          }
    }

    float pm = -1e30f;
#pragma unroll
    for (int kc = 0; kc < 2; ++kc)
#pragma unroll
      for (int b = 0; b < 2; ++b)
#pragma unroll
        for (int r = 0; r < 4; ++r) pm = fmaxf(pm, S[kc][b][r]);
    pm = fmaxf(pm, __shfl_xor(pm, 16, 64));
    pm = fmaxf(pm, __shfl_xor(pm, 32, 64));

    if (__any(pm > mrun + 4.0f)) {  // defer-max rescale
      const float mnew = fmaxf(mrun, pm);
      const float alpha = __expf(mrun - mnew);
      mrun = mnew;
      lrun *= alpha;
      float a4[4];
#pragma unroll
      for (int r = 0; r < 4; ++r) a4[r] = __shfl(alpha, lh * 4 + r, 64);
#pragma unroll
      for (int i = 0; i < 8; ++i)
#pragma unroll
        for (int r = 0; r < 4; ++r) ctx[i][r] *= a4[r];
    }

    bh8 pa[2];
#pragma unroll
    for (int kc = 0; kc < 2; ++kc) {
      union { bh8 v; bf16 e[8]; } pk;
#pragma unroll
      for (int b = 0; b < 2; ++b)
#pragma unroll
        for (int r = 0; r < 4; ++r) {
          const float p = __expf(S[kc][b][r] - mrun);
          lrun += p;
          pk.e[b * 4 + r] = __float2bfloat16(p);
        }
      pa[kc] = pk.v;
    }

#pragma unroll
    for (int kc = 0; kc < 2; ++kc)
#pragma unroll
      for (int dblk = 0; dblk < 8; ++dblk) {
        const int vrow = dblk * 16 + lr;
        const int voff = (vrow * 128 + kc * 64 + lh * 16) ^ ((lr & 7) << 4);
        bh8 vb = *(const bh8*)(Vc + voff);
        ctx[dblk] = MFMA16(pa[kc], vb, ctx[dblk]);
      }

    __builtin_amdgcn_s_barrier();  // reads of cur done; safe to re-stage next iter
    cur ^= 1;
  }
#undef KV_STAGE

  float l = lrun;
  l += __shfl_xor(l, 16, 64);
  l += __shfl_xor(l, 32, 64);
  if (lh == 0) {
    ML[pid * 128 + w * 16 + lr] = mrun;
    ML[pid * 128 + 64 + w * 16 + lr] = l;
  }
#pragma unroll
  for (int dblk = 0; dblk < 8; ++dblk)
#pragma unroll
    for (int r = 0; r < 4; ++r)
      Pctx[(long)pid * 8192 + (w * 16 + lh * 4 + r) * 128 + dblk * 16 + lr] =
          __float2bfloat16(ctx[dblk][r]);
}

// ---------------- merge 2 partials -> normalized ctx (bf16, [t][h*128+d]) ----------------
__global__ __launch_bounds__(256) void attn_merge(const bf16* __restrict__ Pctx,
                                                  const float* __restrict__ ML,
                                                  bf16* __restrict__ out) {
  const int h = blockIdx.x, qb = blockIdx.y;
  const int tid = threadIdx.x;
  const int r = tid >> 2, seg = tid & 3;
  const int pid0 = (h * 32 + qb) * 2;
  const float m0 = ML[pid0 * 128 + r], l0 = ML[pid0 * 128 + 64 + r];
  const float m1 = ML[pid0 * 128 + 128 + r], l1 = ML[pid0 * 128 + 192 + r];
  const float m = fmaxf(m0, m1);
  float a0 = __expf(m0 - m), a1 = __expf(m1 - m);
  const float inv = 1.0f / (l0 * a0 + l1 * a1);
  a0 *= inv;
  a1 *= inv;
  const ushort* p0 = (const ushort*)(Pctx + (long)pid0 * 8192 + r * 128 + seg * 32);
  const ushort* p1 = p0 + 8192;
  bf16* o = out + (long)(qb * 64 + r) * 2048 + h * 128 + seg * 32;
#pragma unroll
  for (int j = 0; j < 4; ++j) {
    union { bh8 v; ushort s[8]; } v0, v1;
    v0.v = *(const bh8*)(p0 + j * 8);
    v1.v = *(const bh8*)(p1 + j * 8);
    union { ushort4 u; bf16 b[4]; } o0, o1;
#pragma unroll
    for (int e = 0; e < 4; ++e) {
      o0.b[e] = __float2bfloat16(bfu2f(v0.s[e]) * a0 + bfu2f(v1.s[e]) * a1);
      o1.b[e] = __float2bfloat16(bfu2f(v0.s[e + 4]) * a0 + bfu2f(v1.s[e + 4]) * a1);
    }
    *(ushort4*)(o + j * 8) = o0.u;
    *(ushort4*)(o + j * 8 + 4) = o1.u;
  }
}

// ---------------- launch ----------------
extern "C" void kernel_launch(void* const* d_in, const int* in_sizes, int n_in,
                              void* d_out, int out_size, void* d_ws, size_t ws_size,
                              hipStream_t stream) {
  const float* hs = (const float*)d_in[0];
  const int* pos = (const int*)d_in[1];
  const float* Wqkv = (const float*)d_in[2];
  const float* Wo = (const float*)d_in[3];
  char* ws = (char*)d_ws;

  bf16* hsb = (bf16*)(ws);
  bf16* ctx = (bf16*)(ws);
  bf16* wqkvT = (bf16*)(ws + (8l << 20));
  bf16* Qb = (bf16*)(ws + (8l << 20));
  bf16* Kb = (bf16*)(ws + (16l << 20));
  bf16* VbT = (bf16*)(ws + (18l << 20));
  bf16* woT = (bf16*)(ws + (20l << 20));
  bf16* qkvP0 = (bf16*)(ws + (28l << 20));
  bf16* qkvP1 = (bf16*)(ws + (40l << 20));
  bf16* Pctx = (bf16*)(ws + (28l << 20));
  float* ML = (float*)(ws + (44l << 20));
  float* outP1 = (float*)(ws + (28l << 20));

  prep<<<14336, 256, 0, stream>>>(hs, hsb, Wqkv, wqkvT, Wo, woT);
  gemm_bt_sk<true><<<dim3(24, 16, 2), 256, 0, stream>>>(hsb, wqkvT, qkvP0, qkvP1,
                                                        2048, 3072, 2048, 16);
  rope_split<<<2048, 256, 0, stream>>>(qkvP0, qkvP1, pos, Qb, Kb, VbT);
  attn_partial<<<dim3(16, 32, 2), 256, 0, stream>>>(Qb, Kb, VbT, Pctx, ML);
  attn_merge<<<dim3(16, 32), 256, 0, stream>>>(Pctx, ML, ctx);
  gemm_bt_sk<false><<<dim3(16, 16, 2), 256, 0, stream>>>(ctx, woT, d_out, outP1,
                                                         2048, 2048, 2048, 16);
  out_reduce<<<4096, 256, 0, stream>>>((float*)d_out, outP1, 2048 * 2048 / 4);
}

// Round 13
// 220.644 us; speedup vs baseline: 1.0547x; 1.0083x over previous
//
#include <hip/hip_runtime.h>
#include <hip/hip_bf16.h>
#include <stdint.h>

typedef __hip_bfloat16 bf16;
typedef __attribute__((ext_vector_type(8))) short bh8;
typedef __attribute__((ext_vector_type(4))) float f32x4;

#define MFMA16(a, b, c) __builtin_amdgcn_mfma_f32_16x16x32_bf16((a), (b), (c), 0, 0, 0)

typedef const __attribute__((address_space(1))) void* gas1_t;
typedef __attribute__((address_space(3))) void* las3_t;

__device__ __forceinline__ void gload_lds16(const void* g, void* l) {
  __builtin_amdgcn_global_load_lds((gas1_t)g, (las3_t)l, 16, 0, 0);
}

__device__ __forceinline__ float bfu2f(unsigned short u) {
  union { unsigned int i; float f; } c;
  c.i = (unsigned int)u << 16;
  return c.f;
}

// ---------------- fused prep: cast hs -> bf16 ; transpose Wqkv, Wo -> bf16 ----------------
__global__ __launch_bounds__(256) void prep(const float* __restrict__ hs, bf16* __restrict__ hsb,
                                            const float* __restrict__ Wqkv,
                                            bf16* __restrict__ wqkvT,
                                            const float* __restrict__ Wo,
                                            bf16* __restrict__ woT) {
  const int b = blockIdx.x, tid = threadIdx.x;
  if (b < 4096) {  // cast 2048x2048 fp32 -> bf16
    const int i = b * 256 + tid;
    float4 v = ((const float4*)hs)[i];
    union { ushort4 u; bf16 bb[4]; } o;
    o.bb[0] = __float2bfloat16(v.x);
    o.bb[1] = __float2bfloat16(v.y);
    o.bb[2] = __float2bfloat16(v.z);
    o.bb[3] = __float2bfloat16(v.w);
    ((ushort4*)hsb)[i] = o.u;
    return;
  }
  __shared__ float tile[32][33];
  const float* W;
  bf16* WT;
  int bx, by, R, C;
  if (b < 4096 + 6144) {  // Wqkv (2048 x 3072) -> (3072 x 2048)
    const int bb = b - 4096;
    bx = bb % 96; by = bb / 96; R = 2048; C = 3072; W = Wqkv; WT = wqkvT;
  } else {  // Wo (2048 x 2048) -> (2048 x 2048)
    const int bb = b - 10240;
    bx = bb % 64; by = bb / 64; R = 2048; C = 2048; W = Wo; WT = woT;
  }
  const int tx = tid & 31, ty = tid >> 5;
#pragma unroll
  for (int p = 0; p < 4; ++p)
    tile[ty + p * 8][tx] = W[(long)(by * 32 + ty + p * 8) * C + bx * 32 + tx];
  __syncthreads();
#pragma unroll
  for (int p = 0; p < 4; ++p)
    WT[(long)(bx * 32 + ty + p * 8) * R + by * 32 + tx] = __float2bfloat16(tile[tx][ty + p * 8]);
}

// ---------------- GEMM split-K=2: C = A * BT^T, BK=64, single-buffer (R8 best: 41us) -------
// 32KB LDS -> 4-5 blocks/CU resident. XOR-swizzled LDS (T2). bf16 partial outputs.
__global__ __launch_bounds__(256) void gemm_bt_sk(const bf16* __restrict__ A,
                                                  const bf16* __restrict__ BT,
                                                  bf16* __restrict__ C0, bf16* __restrict__ C1,
                                                  int M, int N, int Kd, int nKs) {
  __shared__ bf16 As[128 * 64];
  __shared__ bf16 Bs[128 * 64];
  const int tid = threadIdx.x, lane = tid & 63, wid = tid >> 6;
  const int wr = wid >> 1, wc = wid & 1;
  const int bx = blockIdx.x, by = blockIdx.y, z = blockIdx.z;

  f32x4 acc[4][4];
#pragma unroll
  for (int m = 0; m < 4; ++m)
#pragma unroll
    for (int n = 0; n < 4; ++n)
#pragma unroll
      for (int r = 0; r < 4; ++r) acc[m][n][r] = 0.0f;

  const long Abase = (long)(by * 128) * Kd;
  const long Bbase = (long)(bx * 128) * Kd;
  const int lr = lane & 15, lh = lane >> 4;
  const int k00 = z * nKs * 64;

  for (int kt = 0; kt < nKs; ++kt) {
    __syncthreads();
    const int k0 = k00 + kt * 64;
#pragma unroll
    for (int i = 0; i < 4; ++i) {
      const int cb = i * 256 + wid * 64;
      const int c = cb + lane;
      const int row = c >> 3, s = c & 7;
      gload_lds16(A + Abase + (long)row * Kd + k0 + (s ^ (row & 7)) * 8, (char*)As + cb * 16);
      gload_lds16(BT + Bbase + (long)row * Kd + k0 + (s ^ (row & 7)) * 8, (char*)Bs + cb * 16);
    }
    __syncthreads();

#pragma unroll
    for (int kk = 0; kk < 2; ++kk) {
      bh8 af[4], bfv[4];
#pragma unroll
      for (int m = 0; m < 4; ++m)
        af[m] = *(const bh8*)((const char*)As +
                              (((wr * 64 + m * 16 + lr) * 128 + kk * 64 + lh * 16) ^
                               ((lr & 7) << 4)));
#pragma unroll
      for (int n = 0; n < 4; ++n)
        bfv[n] = *(const bh8*)((const char*)Bs +
                               (((wc * 64 + n * 16 + lr) * 128 + kk * 64 + lh * 16) ^
                                ((lr & 7) << 4)));
#pragma unroll
      for (int m = 0; m < 4; ++m)
#pragma unroll
        for (int n = 0; n < 4; ++n) acc[m][n] = MFMA16(af[m], bfv[n], acc[m][n]);
    }
  }

  bf16* P = (z == 0) ? C0 : C1;
  const int r0 = by * 128 + wr * 64, c0i = bx * 128 + wc * 64;
  const int lrow = lh * 4;
#pragma unroll
  for (int m = 0; m < 4; ++m)
#pragma unroll
    for (int n = 0; n < 4; ++n)
#pragma unroll
      for (int r = 0; r < 4; ++r)
        P[(long)(r0 + m * 16 + lrow + r) * N + c0i + n * 16 + lr] =
            __float2bfloat16(acc[m][n][r]);
}

// ---------------- out = p0 + p1 (bf16 partials -> fp32, vectorized) ----------------
__global__ __launch_bounds__(256) void out_reduce2(float* __restrict__ out,
                                                   const bf16* __restrict__ p0,
                                                   const bf16* __restrict__ p1, int n8) {
  int i = blockIdx.x * 256 + threadIdx.x;
  if (i >= n8) return;
  union { bh8 v; ushort s[8]; } a, b;
  a.v = *(const bh8*)(p0 + (long)i * 8);
  b.v = *(const bh8*)(p1 + (long)i * 8);
  float4 o0, o1;
#pragma unroll
  for (int e = 0; e < 4; ++e) {
    (&o0.x)[e] = bfu2f(a.s[e]) + bfu2f(b.s[e]);
    (&o1.x)[e] = bfu2f(a.s[e + 4]) + bfu2f(b.s[e + 4]);
  }
  ((float4*)out)[i * 2] = o0;
  ((float4*)out)[i * 2 + 1] = o1;
}

// ---------------- RoPE (NeoX) + sum 2 bf16 qkv partials + split ----------------
__global__ __launch_bounds__(256) void rope_split(const bf16* __restrict__ P0,
                                                  const bf16* __restrict__ P1,
                                                  const int* __restrict__ pos_ids,
                                                  bf16* __restrict__ Qb, bf16* __restrict__ Kb,
                                                  bf16* __restrict__ VbT) {
  __shared__ float lcs[64], lsn[64];
  const int t = blockIdx.x;
  const int tid = threadIdx.x;
  const float pos = (float)pos_ids[t];
  const float qscale = 0.08838834764831845f;  // 1/sqrt(128)
  const ushort* r0 = (const ushort*)(P0 + (long)t * 3072);
  const ushort* r1 = (const ushort*)(P1 + (long)t * 3072);

  if (tid < 64) {
    const float inv = exp2f((float)tid * -0.2076205059304594f);  // 10000^(-d/64)
    float s, c;
    __sincosf(pos * inv, &s, &c);
    lcs[tid] = c;
    lsn[tid] = s;
  }
  __syncthreads();

  for (int i = tid; i < 512; i += 256) {
    const int kvh = i >> 7, d = i & 127;
    const float v = bfu2f(r0[2560 + i]) + bfu2f(r1[2560 + i]);
    VbT[(long)(kvh * 128 + d) * 2048 + t] = __float2bfloat16(v);
  }
  for (int i = tid; i < 1280; i += 256) {
    const int hh = i >> 6, d = i & 63;
    const float c = lcs[d], s = lsn[d];
    const float x1 = bfu2f(r0[hh * 128 + d]) + bfu2f(r1[hh * 128 + d]);
    const float x2 = bfu2f(r0[hh * 128 + d + 64]) + bfu2f(r1[hh * 128 + d + 64]);
    const float o1 = x1 * c - x2 * s, o2 = x2 * c + x1 * s;
    if (hh < 16) {
      Qb[(long)t * 2048 + hh * 128 + d] = __float2bfloat16(o1 * qscale);
      Qb[(long)t * 2048 + hh * 128 + d + 64] = __float2bfloat16(o2 * qscale);
    } else {
      Kb[t * 512 + (hh - 16) * 128 + d] = __float2bfloat16(o1);
      Kb[t * 512 + (hh - 16) * 128 + d + 64] = __float2bfloat16(o2);
    }
  }
}

// ---------------- Flash attention partials: swapped-QK in-reg softmax, single-buffer ---------
// 32KB LDS + 104 VGPR -> 4 blocks/CU resident (vs 2 with dbuf).
// launch_bounds(256,2): ",4" would cap VGPR at 64 -> scratch spills (R6 lesson).
__global__ __launch_bounds__(256, 2) void attn_partial(const bf16* __restrict__ Qb,
                                                       const bf16* __restrict__ Kb,
                                                       const bf16* __restrict__ VbT,
                                                       bf16* __restrict__ Pctx,
                                                       float* __restrict__ ML) {
  const int h = blockIdx.x;
  const int qb = 31 - blockIdx.y;  // heavy blocks dispatch first
  const int z = blockIdx.z;
  const int kh = h >> 2;
  const int tid = threadIdx.x, lane = tid & 63, w = tid >> 6;
  const int pid = (h * 32 + qb) * 2 + z;

  const int nt = qb + 1;
  const int half = (nt + 1) >> 1;
  const int kt0 = z * half;
  const int kt1 = (z == 0) ? half : nt;

  if (kt0 >= kt1) {  // empty chunk: neutral ML + zeroed partial
    if (tid < 64) {
      ML[pid * 128 + tid] = -1e30f;
      ML[pid * 128 + 64 + tid] = 0.0f;
    }
    ushort4 z4 = make_ushort4(0, 0, 0, 0);
    ushort4* pz = (ushort4*)(Pctx + (long)pid * 8192);
    for (int j = tid; j < 2048; j += 256) pz[j] = z4;
    return;
  }

  __shared__ bf16 Kl[64 * 128];  // swizzle bits: (row&3)|((row&8)>>1)
  __shared__ bf16 Vt[128 * 64];  // swizzle bits: row&7

  const int lr = lane & 15, lh = lane >> 4;
  const int q0w = qb * 64 + w * 16;

  bh8 qf[4];
#pragma unroll
  for (int dc = 0; dc < 4; ++dc)
    qf[dc] = *(const bh8*)&Qb[(long)(q0w + lr) * 2048 + h * 128 + dc * 32 + lh * 8];

  f32x4 ctx[8];
#pragma unroll
  for (int i = 0; i < 8; ++i)
#pragma unroll
    for (int r = 0; r < 4; ++r) ctx[i][r] = 0.0f;
  float mrun = -1e30f, lrun = 0.0f;

  for (int kt = kt0; kt < kt1; ++kt) {
    __syncthreads();
    const long Kbase = ((long)(kt * 64) * 4 + kh) * 128;
#pragma unroll
    for (int i = 0; i < 4; ++i) {
      const int cb = i * 256 + w * 64;
      const int c = cb + lane;
      const int krow = c >> 4, s = c & 15;
      const int g = s ^ ((krow & 3) | ((krow & 8) >> 1));
      gload_lds16(Kb + Kbase + (long)krow * 512 + g * 8, (char*)Kl + cb * 16);
    }
    const long Vbase = (long)kh * 128 * 2048 + kt * 64;
#pragma unroll
    for (int i = 0; i < 4; ++i) {
      const int cb = i * 256 + w * 64;
      const int c = cb + lane;
      const int vrow = c >> 3, s = c & 7;
      gload_lds16(VbT + Vbase + (long)vrow * 2048 + (s ^ (vrow & 7)) * 8, (char*)Vt + cb * 16);
    }
    __syncthreads();

    // S^T = K . Q^T; lane (lr,lh) reg (kc,b,r): S[key=kc*32+lh*8+b*4+r][q=lr]
    f32x4 S[2][2];
#pragma unroll
    for (int kc = 0; kc < 2; ++kc)
#pragma unroll
      for (int b = 0; b < 2; ++b) {
#pragma unroll
        for (int r = 0; r < 4; ++r) S[kc][b][r] = 0.0f;
        const int key = kc * 32 + ((lr >> 2) << 3) + b * 4 + (lr & 3);
        const int kbase = key * 256 + lh * 16;
#pragma unroll
        for (int dc = 0; dc < 4; ++dc) {
          bh8 kf = *(const bh8*)((const char*)Kl + ((kbase + dc * 64) ^ ((lr & 7) << 4)));
          S[kc][b] = MFMA16(kf, qf[dc], S[kc][b]);
        }
      }

    if (kt == qb) {  // causal mask on the diagonal tile only
      const int qg = q0w + lr;
#pragma unroll
      for (int kc = 0; kc < 2; ++kc)
#pragma unroll
        for (int b = 0; b < 2; ++b)
#pragma unroll
          for (int r = 0; r < 4; ++r) {
            const int kg = kt * 64 + kc * 32 + lh * 8 + b * 4 + r;
            if (kg > qg) S[kc][b][r] = -1e30f;
          }
    }

    float pm = -1e30f;
#pragma unroll
    for (int kc = 0; kc < 2; ++kc)
#pragma unroll
      for (int b = 0; b < 2; ++b)
#pragma unroll
        for (int r = 0; r < 4; ++r) pm = fmaxf(pm, S[kc][b][r]);
    pm = fmaxf(pm, __shfl_xor(pm, 16, 64));
    pm = fmaxf(pm, __shfl_xor(pm, 32, 64));

    if (__any(pm > mrun + 4.0f)) {  // defer-max rescale
      const float mnew = fmaxf(mrun, pm);
      const float alpha = __expf(mrun - mnew);
      mrun = mnew;
      lrun *= alpha;
      float a4[4];
#pragma unroll
      for (int r = 0; r < 4; ++r) a4[r] = __shfl(alpha, lh * 4 + r, 64);
#pragma unroll
      for (int i = 0; i < 8; ++i)
#pragma unroll
        for (int r = 0; r < 4; ++r) ctx[i][r] *= a4[r];
    }

    bh8 pa[2];
#pragma unroll
    for (int kc = 0; kc < 2; ++kc) {
      union { bh8 v; bf16 e[8]; } pk;
#pragma unroll
      for (int b = 0; b < 2; ++b)
#pragma unroll
        for (int r = 0; r < 4; ++r) {
          const float p = __expf(S[kc][b][r] - mrun);
          lrun += p;
          pk.e[b * 4 + r] = __float2bfloat16(p);
        }
      pa[kc] = pk.v;
    }

#pragma unroll
    for (int kc = 0; kc < 2; ++kc)
#pragma unroll
      for (int dblk = 0; dblk < 8; ++dblk) {
        const int vrow = dblk * 16 + lr;
        const int voff = (vrow * 128 + kc * 64 + lh * 16) ^ ((lr & 7) << 4);
        bh8 vb = *(const bh8*)((const char*)Vt + voff);
        ctx[dblk] = MFMA16(pa[kc], vb, ctx[dblk]);
      }
  }

  float l = lrun;
  l += __shfl_xor(l, 16, 64);
  l += __shfl_xor(l, 32, 64);
  if (lh == 0) {
    ML[pid * 128 + w * 16 + lr] = mrun;
    ML[pid * 128 + 64 + w * 16 + lr] = l;
  }
#pragma unroll
  for (int dblk = 0; dblk < 8; ++dblk)
#pragma unroll
    for (int r = 0; r < 4; ++r)
      Pctx[(long)pid * 8192 + (w * 16 + lh * 4 + r) * 128 + dblk * 16 + lr] =
          __float2bfloat16(ctx[dblk][r]);
}

// ---------------- merge 2 partials -> normalized ctx (bf16, [t][h*128+d]) ----------------
__global__ __launch_bounds__(256) void attn_merge(const bf16* __restrict__ Pctx,
                                                  const float* __restrict__ ML,
                                                  bf16* __restrict__ out) {
  const int h = blockIdx.x, qb = blockIdx.y;
  const int tid = threadIdx.x;
  const int r = tid >> 2, seg = tid & 3;
  const int pid0 = (h * 32 + qb) * 2;
  const float m0 = ML[pid0 * 128 + r], l0 = ML[pid0 * 128 + 64 + r];
  const float m1 = ML[pid0 * 128 + 128 + r], l1 = ML[pid0 * 128 + 192 + r];
  const float m = fmaxf(m0, m1);
  float a0 = __expf(m0 - m), a1 = __expf(m1 - m);
  const float inv = 1.0f / (l0 * a0 + l1 * a1);
  a0 *= inv;
  a1 *= inv;
  const ushort* p0 = (const ushort*)(Pctx + (long)pid0 * 8192 + r * 128 + seg * 32);
  const ushort* p1 = p0 + 8192;
  bf16* o = out + (long)(qb * 64 + r) * 2048 + h * 128 + seg * 32;
#pragma unroll
  for (int j = 0; j < 4; ++j) {
    union { bh8 v; ushort s[8]; } v0, v1;
    v0.v = *(const bh8*)(p0 + j * 8);
    v1.v = *(const bh8*)(p1 + j * 8);
    union { ushort4 u; bf16 b[4]; } o0, o1;
#pragma unroll
    for (int e = 0; e < 4; ++e) {
      o0.b[e] = __float2bfloat16(bfu2f(v0.s[e]) * a0 + bfu2f(v1.s[e]) * a1);
      o1.b[e] = __float2bfloat16(bfu2f(v0.s[e + 4]) * a0 + bfu2f(v1.s[e + 4]) * a1);
    }
    *(ushort4*)(o + j * 8) = o0.u;
    *(ushort4*)(o + j * 8 + 4) = o1.u;
  }
}

// ---------------- launch ----------------
extern "C" void kernel_launch(void* const* d_in, const int* in_sizes, int n_in,
                              void* d_out, int out_size, void* d_ws, size_t ws_size,
                              hipStream_t stream) {
  const float* hs = (const float*)d_in[0];
  const int* pos = (const int*)d_in[1];
  const float* Wqkv = (const float*)d_in[2];
  const float* Wo = (const float*)d_in[3];
  char* ws = (char*)d_ws;

  // workspace layout:
  // [0,8): hsb -> later ctx
  // [8,20): wqkvT -> later Qb[8,16)+Kb[16,18)+VbT[18,20)
  // [20,28): woT
  // [28,40)+[40,52): qkv bf16 partials -> later Pctx[28,44)+ML[44,44.5)
  //   -> later (after merge) gemm2 bf16 partials oP0[28,36)+oP1[36,44)
  bf16* hsb = (bf16*)(ws);
  bf16* ctx = (bf16*)(ws);
  bf16* wqkvT = (bf16*)(ws + (8l << 20));
  bf16* Qb = (bf16*)(ws + (8l << 20));
  bf16* Kb = (bf16*)(ws + (16l << 20));
  bf16* VbT = (bf16*)(ws + (18l << 20));
  bf16* woT = (bf16*)(ws + (20l << 20));
  bf16* qkvP0 = (bf16*)(ws + (28l << 20));
  bf16* qkvP1 = (bf16*)(ws + (40l << 20));
  bf16* Pctx = (bf16*)(ws + (28l << 20));
  float* ML = (float*)(ws + (44l << 20));
  bf16* oP0 = (bf16*)(ws + (28l << 20));
  bf16* oP1 = (bf16*)(ws + (36l << 20));

  prep<<<14336, 256, 0, stream>>>(hs, hsb, Wqkv, wqkvT, Wo, woT);
  gemm_bt_sk<<<dim3(24, 16, 2), 256, 0, stream>>>(hsb, wqkvT, qkvP0, qkvP1, 2048, 3072, 2048,
                                                  16);
  rope_split<<<2048, 256, 0, stream>>>(qkvP0, qkvP1, pos, Qb, Kb, VbT);
  attn_partial<<<dim3(16, 32, 2), 256, 0, stream>>>(Qb, Kb, VbT, Pctx, ML);
  attn_merge<<<dim3(16, 32), 256, 0, stream>>>(Pctx, ML, ctx);
  gemm_bt_sk<<<dim3(16, 16, 2), 256, 0, stream>>>(ctx, woT, oP0, oP1, 2048, 2048, 2048, 16);
  out_reduce2<<<2048, 256, 0, stream>>>((float*)d_out, oP0, oP1, 2048 * 2048 / 8);
}